// Round 4
// baseline (241.989 us; speedup 1.0000x reference)
//
#include <hip/hip_runtime.h>

// GPT2 grouped-query attention, bf16 MFMA pipeline, round 11.
// R11: qkv/out GEMMs converted to attn5's proven single-barrier LDS
// double-buffer: stage tile t+1 at top of step t, compute t, one
// __syncthreads at step end (its implicit vmcnt(0) waits on loads that
// flew under the MFMA phase). BK=64 + zero-conflict swizzle kept.
// 64KB LDS -> 2 blocks/CU; qkv grid 1536 = 3 even rounds, out 512 = 1.
// attn5/convert unchanged from R10.
// ws (u16 elems): q_att[8M] | k_att[8M] | v_t[8M] | Xb/ctx[8M] | Wcat[3M] | Wob[1M]

typedef __attribute__((ext_vector_type(8))) short short8;
typedef __attribute__((ext_vector_type(4))) float f32x4;
typedef unsigned int u32;
typedef unsigned short u16;

#define MFMA16(a, b, c) __builtin_amdgcn_mfma_f32_16x16x32_bf16((a), (b), (c), 0, 0, 0)

union S8 { short8 s; uint2 v[2]; u32 u[4]; };

__device__ __forceinline__ u32 f2bf1(float x) {
    union { float f; u32 u; } v; v.f = x;
    return (v.u + 0x7fffu + ((v.u >> 16) & 1u)) >> 16;   // RNE
}

__device__ __forceinline__ u32 cvtpk(float lo, float hi) {
    u32 r;
    asm("v_cvt_pk_bf16_f32 %0, %1, %2" : "=v"(r) : "v"(lo), "v"(hi));
    return r;
}

__device__ __forceinline__ void gld16(u16* lds, const u16* g) {
    __builtin_amdgcn_global_load_lds(
        (const __attribute__((address_space(1))) unsigned int*)(g),
        (__attribute__((address_space(3))) unsigned int*)(lds),
        16, 0, 0);
}

// ---------------------------------------------------------------------------
// Kernel 0: fp32 -> bf16 convert.
// ---------------------------------------------------------------------------
__global__ __launch_bounds__(256) void convert(
    const float* __restrict__ X, const float* __restrict__ Wq,
    const float* __restrict__ Wk, const float* __restrict__ Wv,
    const float* __restrict__ Wo,
    u16* __restrict__ Xb, u16* __restrict__ Wcat, u16* __restrict__ Wob)
{
    const size_t M8 = 8388608, M1 = 1048576;
    size_t i = ((size_t)blockIdx.x * 256 + threadIdx.x) * 16;
    const float* src; u16* dst;
    if (i < M8)              { src = X  + i;                dst = Xb   + i; }
    else if (i < M8 + M1)    { src = Wq + (i - M8);         dst = Wcat + (i - M8); }
    else if (i < M8 + 2*M1)  { src = Wk + (i - M8 - M1);    dst = Wcat + (i - M8); }
    else if (i < M8 + 3*M1)  { src = Wv + (i - M8 - 2*M1);  dst = Wcat + (i - M8); }
    else                     { src = Wo + (i - M8 - 3*M1);  dst = Wob  + (i - M8 - 3*M1); }
#pragma unroll
    for (int j = 0; j < 2; ++j) {
        float4 a = ((const float4*)src)[2 * j];
        float4 b = ((const float4*)src)[2 * j + 1];
        uint4 o;
        o.x = f2bf1(a.x) | (f2bf1(a.y) << 16);
        o.y = f2bf1(a.z) | (f2bf1(a.w) << 16);
        o.z = f2bf1(b.x) | (f2bf1(b.y) << 16);
        o.w = f2bf1(b.z) | (f2bf1(b.w) << 16);
        ((uint4*)dst)[j] = o;
    }
}

// ---------------------------------------------------------------------------
// Kernel 1: fused QKV GEMM. C[8192][3072] = Xb @ Wcat^T. 128x128 tile, BK=64,
// swizzled dbuf LDS, ONE barrier per K-step (stage t+1 under compute t).
// q/k layout: [bh][g][dp'] with dp' = 2*dh + (s&1); v_t: [bh][dp][g-sigma].
// ---------------------------------------------------------------------------
__global__ __launch_bounds__(256, 2) void qkv_gemm10(
    const u16* __restrict__ Xb, const u16* __restrict__ Wcat,
    const float* __restrict__ b0, const float* __restrict__ b1,
    const float* __restrict__ b2,
    u16* __restrict__ q_att, u16* __restrict__ k_att, u16* __restrict__ v_t)
{
    const int nb = blockIdx.x, mb = blockIdx.y;
    const int mat = nb >> 3;

    __shared__ __align__(16) u16 As[2][128 * 64];   // 32 KB
    __shared__ __align__(16) u16 Bs[2][128 * 64];   // 32 KB

    const int t = threadIdx.x, wave = t >> 6, lane = t & 63;
    const int l15 = lane & 15, quad = lane >> 4;
    const int wm = (wave >> 1) * 64, wn = (wave & 1) * 64;

    // staging: thread t covers row (c*32 + t>>3), 16B chunk (t&7); source
    // chunk pre-swizzled by row&7 so LDS holds [row][chunk ^ (row&7)].
    const int srow = t >> 3;                               // 0..31
    const int scol = ((t & 7) ^ (srow & 7)) * 8;           // swizzled src chunk

    const u16* Ab = Xb   + (size_t)(mb * 128) * 1024;
    const u16* Bb = Wcat + (size_t)(nb * 128) * 1024;

    const int swz = l15 & 7;

#define QSTAGE(pp, k0_) do {                                                  \
        _Pragma("unroll")                                                     \
        for (int c_ = 0; c_ < 4; ++c_) {                                      \
            size_t so_ = (size_t)(c_ * 32 + srow) * 1024 + (k0_) + scol;      \
            gld16(&As[(pp)][wave * 512 + c_ * 2048], Ab + so_);               \
            gld16(&Bs[(pp)][wave * 512 + c_ * 2048], Bb + so_);               \
        }                                                                     \
    } while (0)

    f32x4 acc[4][4] = {};

    QSTAGE(0, 0);
    __syncthreads();

    for (int kt = 0; kt < 16; ++kt) {
        const int p = kt & 1;
        if (kt + 1 < 16) QSTAGE(p ^ 1, (kt + 1) * 64);   // flies under compute
        const u16* Asp = &As[p][0];
        const u16* Bsp = &Bs[p][0];

#pragma unroll
        for (int ks = 0; ks < 2; ++ks) {
            short8 af[4], bf[4];
            const int ck = ((ks * 4 + quad) ^ swz) * 8;
#pragma unroll
            for (int mt = 0; mt < 4; ++mt)
                af[mt] = *(const short8*)(Asp + (wm + mt * 16 + l15) * 64 + ck);
#pragma unroll
            for (int nt = 0; nt < 4; ++nt)
                bf[nt] = *(const short8*)(Bsp + (wn + nt * 16 + l15) * 64 + ck);
#pragma unroll
            for (int mt = 0; mt < 4; ++mt)
#pragma unroll
                for (int nt = 0; nt < 4; ++nt)
                    acc[mt][nt] = MFMA16(af[mt], bf[nt], acc[mt][nt]);
        }

        if (kt + 1 < 16) __syncthreads();   // drains the t+1 stage (overlapped)
    }
#undef QSTAGE

    const float* bias = (mat == 0) ? b0 : (mat == 1) ? b1 : b2;
    const float scl = (mat == 0) ? 0.125f : 1.0f;
#pragma unroll
    for (int nt = 0; nt < 4; ++nt) {
        int colm = (nb & 7) * 128 + wn + nt * 16 + l15;   // feature = h*64+dh
        float bv = bias[colm];
        int h = colm >> 6, dh = colm & 63;
#pragma unroll
        for (int mt = 0; mt < 4; ++mt) {
            int row0 = mb * 128 + wm + mt * 16 + quad * 4;
            int b = row0 >> 11, s0 = row0 & 2047;
            int bh = b * 16 + h, g0 = s0 >> 1;                // even
            float v0 = (acc[mt][nt][0] + bv) * scl, v1 = (acc[mt][nt][1] + bv) * scl;
            float v2 = (acc[mt][nt][2] + bv) * scl, v3 = (acc[mt][nt][3] + bv) * scl;
            if (mat == 2) {
                u32 w0 = f2bf1(v0) | (f2bf1(v2) << 16);
                u32 w1 = f2bf1(v1) | (f2bf1(v3) << 16);
                int j6 = g0 & 63;
                int gp = (g0 & ~63) + (j6 & 32) + ((j6 >> 2) & 3) * 8
                       + ((j6 >> 4) & 1) * 4 + (j6 & 3);      // sigma-permuted
                *(u32*)(v_t + ((size_t)(bh * 128 + dh) * 1024 + gp)) = w0;
                *(u32*)(v_t + ((size_t)(bh * 128 + dh + 64) * 1024 + gp)) = w1;
            } else {
                u16* dst = (mat == 0) ? q_att : k_att;
                u32 w0 = f2bf1(v0) | (f2bf1(v1) << 16);
                u32 w1 = f2bf1(v2) | (f2bf1(v3) << 16);
                size_t base = ((size_t)bh * 1024 + g0) * 128 + 2 * dh;
                *(u32*)(dst + base) = w0;
                *(u32*)(dst + base + 128) = w1;
            }
        }
    }
}

// ---------------------------------------------------------------------------
// Kernel 2: flash attention, R10 structure (unchanged). QBLK=128/block,
// dbuf K/V LDS, shared ds_reads across 2 q-groups, cvt_pk packing,
// defer-max (THR=8), setprio on MFMA. grid (64 bh, 8 qb).
// ---------------------------------------------------------------------------
__global__ __launch_bounds__(256, 2) void attn5(
    const u16* __restrict__ q_att, const u16* __restrict__ k_att,
    const u16* __restrict__ v_t, u16* __restrict__ ctx)
{
    const int bh = blockIdx.x, qb = blockIdx.y;
    const u16* Q = q_att + (size_t)bh * 131072;
    const u16* K = k_att + (size_t)bh * 131072;
    const u16* V = v_t  + (size_t)bh * 131072;     // [d'=128][g-sigma-permuted]

    __shared__ __align__(16) u16 Ks[2][64 * 128];  // 32 KB
    __shared__ __align__(16) u16 Vs[2][128 * 64];  // 32 KB

    const int t = threadIdx.x, wave = t >> 6, lane = t & 63;
    const int l15 = lane & 15, quad = lane >> 4;

    int offK[4], offV[4];
#pragma unroll
    for (int j = 0; j < 4; ++j) {
        int ck = wave * 4 + j;
        int rowK = ck * 4 + (lane >> 4);                       // 0..63
        offK[j] = rowK * 128 + (((lane & 15) ^ (rowK & 15)) * 8);
        int rowV = ck * 8 + (lane >> 3);                       // d' 0..127
        offV[j] = rowV * 1024 + (((lane & 7) ^ ((lane >> 3) & 7)) * 8);
    }

#define ASTAGE(pp, kt) do {                                                   \
        const u16* Kt_ = K + (size_t)(kt) * 8192;                             \
        const u16* Vt_ = V + (size_t)(kt) * 64;                               \
        _Pragma("unroll")                                                     \
        for (int j_ = 0; j_ < 4; ++j_) {                                      \
            gld16(&Ks[(pp)][(wave * 4 + j_) * 512], Kt_ + offK[j_]);          \
            gld16(&Vs[(pp)][(wave * 4 + j_) * 512], Vt_ + offV[j_]);          \
        }                                                                     \
    } while (0)

    short8 bq[2][4];
#pragma unroll
    for (int qg = 0; qg < 2; ++qg) {
        const int qr = qb * 128 + wave * 32 + qg * 16 + l15;
#pragma unroll
        for (int kb = 0; kb < 4; ++kb)
            bq[qg][kb] = *(const short8*)(Q + (size_t)qr * 128 + kb * 32 + quad * 8);
    }

    f32x4 accO[2][8] = {};
    float m_i[2] = {-1e30f, -1e30f}, l_i[2] = {0.0f, 0.0f};

    ASTAGE(0, 0);
    __syncthreads();

    for (int kt = 0; kt < 16; ++kt) {
        const int p = kt & 1;
        if (kt + 1 < 16) ASTAGE(p ^ 1, kt + 1);
        const u16* Ksp = &Ks[p][0];
        const u16* Vsp = &Vs[p][0];

        f32x4 accS[2][4] = {};
        __builtin_amdgcn_s_setprio(1);
#pragma unroll
        for (int kf = 0; kf < 4; ++kf)
#pragma unroll
            for (int kb = 0; kb < 4; ++kb) {
                short8 ak = *(const short8*)(Ksp + (kf * 16 + l15) * 128
                                             + (((kb * 4 + quad) ^ l15) * 8));
                accS[0][kf] = MFMA16(ak, bq[0][kb], accS[0][kf]);
                accS[1][kf] = MFMA16(ak, bq[1][kb], accS[1][kf]);
            }
        __builtin_amdgcn_s_setprio(0);

        u32 pb[2][8];
#pragma unroll
        for (int qg = 0; qg < 2; ++qg) {
            float mloc = -1e30f;
#pragma unroll
            for (int kf = 0; kf < 4; ++kf)
                mloc = fmaxf(mloc, fmaxf(fmaxf(accS[qg][kf][0], accS[qg][kf][1]),
                                         fmaxf(accS[qg][kf][2], accS[qg][kf][3])));
            mloc = fmaxf(mloc, __shfl_xor(mloc, 16));
            mloc = fmaxf(mloc, __shfl_xor(mloc, 32));

            if (!__all(mloc - m_i[qg] <= 8.0f)) {
                float mn = fmaxf(m_i[qg], mloc);
                float alpha = __expf(m_i[qg] - mn);
#pragma unroll
                for (int f = 0; f < 8; ++f) {
                    accO[qg][f][0] *= alpha; accO[qg][f][1] *= alpha;
                    accO[qg][f][2] *= alpha; accO[qg][f][3] *= alpha;
                }
                l_i[qg] *= alpha;
                m_i[qg] = mn;
            }

            float lsum = 0.0f;
            const float mi = m_i[qg];
#pragma unroll
            for (int kf = 0; kf < 4; ++kf) {
                float p0 = __expf(accS[qg][kf][0] - mi);
                float p1 = __expf(accS[qg][kf][1] - mi);
                float p2 = __expf(accS[qg][kf][2] - mi);
                float p3 = __expf(accS[qg][kf][3] - mi);
                lsum += (p0 + p1) + (p2 + p3);
                pb[qg][kf * 2]     = cvtpk(p0, p1);
                pb[qg][kf * 2 + 1] = cvtpk(p2, p3);
            }
            lsum += __shfl_xor(lsum, 16);
            lsum += __shfl_xor(lsum, 32);
            l_i[qg] += lsum;
        }

        S8 bp00, bp01, bp10, bp11;
        bp00.u[0] = pb[0][0]; bp00.u[1] = pb[0][1]; bp00.u[2] = pb[0][2]; bp00.u[3] = pb[0][3];
        bp01.u[0] = pb[0][4]; bp01.u[1] = pb[0][5]; bp01.u[2] = pb[0][6]; bp01.u[3] = pb[0][7];
        bp10.u[0] = pb[1][0]; bp10.u[1] = pb[1][1]; bp10.u[2] = pb[1][2]; bp10.u[3] = pb[1][3];
        bp11.u[0] = pb[1][4]; bp11.u[1] = pb[1][5]; bp11.u[2] = pb[1][6]; bp11.u[3] = pb[1][7];
        const int l7 = l15 & 7;
        __builtin_amdgcn_s_setprio(1);
#pragma unroll
        for (int df = 0; df < 8; ++df) {
            const u16* vrow = Vsp + (df * 16 + l15) * 64;
            short8 av0 = *(const short8*)(vrow + ((quad ^ l7) * 8));
            short8 av1 = *(const short8*)(vrow + (((quad + 4) ^ l7) * 8));
            accO[0][df] = MFMA16(av0, bp00.s, accO[0][df]);
            accO[0][df] = MFMA16(av1, bp01.s, accO[0][df]);
            accO[1][df] = MFMA16(av0, bp10.s, accO[1][df]);
            accO[1][df] = MFMA16(av1, bp11.s, accO[1][df]);
        }
        __builtin_amdgcn_s_setprio(0);

        if (kt + 1 < 16) __syncthreads();
    }
#undef ASTAGE

    const int h = bh & 15, b = bh >> 4;
#pragma unroll
    for (int qg = 0; qg < 2; ++qg) {
        const int qr = qb * 128 + wave * 32 + qg * 16 + l15;
        float inv = 1.0f / l_i[qg];
        size_t base = ((size_t)(b * 2048 + 2 * qr + (h >> 3))) * 1024 + (h & 7) * 128;
#pragma unroll
        for (int df = 0; df < 8; ++df) {
            int dp = df * 16 + quad * 4;
            uint2 w;
            w.x = f2bf1(accO[qg][df][0] * inv) | (f2bf1(accO[qg][df][1] * inv) << 16);
            w.y = f2bf1(accO[qg][df][2] * inv) | (f2bf1(accO[qg][df][3] * inv) << 16);
            *(uint2*)(ctx + base + dp) = w;
        }
    }
}

// ---------------------------------------------------------------------------
// Kernel 3: out = ctx(bf16) @ Wob^T + bo -> fp32. Same dbuf single-barrier
// treatment as qkv_gemm10. grid (8,64) = 512 blocks = 1 round at 2/CU.
// ---------------------------------------------------------------------------
__global__ __launch_bounds__(256, 2) void out_gemm10(
    const u16* __restrict__ ctx, const u16* __restrict__ Wob,
    const float* __restrict__ bo, float* __restrict__ out)
{
    const int nb = blockIdx.x, mb = blockIdx.y;
    __shared__ __align__(16) u16 As[2][128 * 64];
    __shared__ __align__(16) u16 Bs[2][128 * 64];
    const int t = threadIdx.x, wave = t >> 6, lane = t & 63;
    const int l15 = lane & 15, quad = lane >> 4;
    const int wm = (wave >> 1) * 64, wn = (wave & 1) * 64;

    const int srow = t >> 3;
    const int scol = ((t & 7) ^ (srow & 7)) * 8;

    const u16* Ab = ctx + (size_t)(mb * 128) * 1024;
    const u16* Bb = Wob + (size_t)(nb * 128) * 1024;

    const int swz = l15 & 7;

#define OSTAGE(pp, k0_) do {                                                  \
        _Pragma("unroll")                                                     \
        for (int c_ = 0; c_ < 4; ++c_) {                                      \
            size_t so_ = (size_t)(c_ * 32 + srow) * 1024 + (k0_) + scol;      \
            gld16(&As[(pp)][wave * 512 + c_ * 2048], Ab + so_);               \
            gld16(&Bs[(pp)][wave * 512 + c_ * 2048], Bb + so_);               \
        }                                                                     \
    } while (0)

    f32x4 acc[4][4] = {};

    OSTAGE(0, 0);
    __syncthreads();

    for (int kt = 0; kt < 16; ++kt) {
        const int p = kt & 1;
        if (kt + 1 < 16) OSTAGE(p ^ 1, (kt + 1) * 64);
        const u16* Asp = &As[p][0];
        const u16* Bsp = &Bs[p][0];

#pragma unroll
        for (int ks = 0; ks < 2; ++ks) {
            short8 af[4], bf[4];
            const int ck = ((ks * 4 + quad) ^ swz) * 8;
#pragma unroll
            for (int mt = 0; mt < 4; ++mt)
                af[mt] = *(const short8*)(Asp + (wm + mt * 16 + l15) * 64 + ck);
#pragma unroll
            for (int nt = 0; nt < 4; ++nt)
                bf[nt] = *(const short8*)(Bsp + (wn + nt * 16 + l15) * 64 + ck);
#pragma unroll
            for (int mt = 0; mt < 4; ++mt)
#pragma unroll
                for (int nt = 0; nt < 4; ++nt)
                    acc[mt][nt] = MFMA16(af[mt], bf[nt], acc[mt][nt]);
        }

        if (kt + 1 < 16) __syncthreads();
    }
#undef OSTAGE

#pragma unroll
    for (int nt = 0; nt < 4; ++nt) {
        int col = nb * 128 + wn + nt * 16 + l15;
        float bv = bo[col];
#pragma unroll
        for (int mt = 0; mt < 4; ++mt)
#pragma unroll
            for (int r = 0; r < 4; ++r) {
                int row = mb * 128 + wm + mt * 16 + quad * 4 + r;
                out[(size_t)row * 1024 + col] = acc[mt][nt][r] + bv;
            }
    }
}

// ---------------------------------------------------------------------------
extern "C" void kernel_launch(void* const* d_in, const int* in_sizes, int n_in,
                              void* d_out, int out_size, void* d_ws, size_t ws_size,
                              hipStream_t stream)
{
    const float* X  = (const float*)d_in[0];
    const float* Wq = (const float*)d_in[1];
    const float* bq = (const float*)d_in[2];
    const float* Wk = (const float*)d_in[3];
    const float* bk = (const float*)d_in[4];
    const float* Wv = (const float*)d_in[5];
    const float* bv = (const float*)d_in[6];
    const float* Wo = (const float*)d_in[7];
    const float* bo = (const float*)d_in[8];

    const size_t M8 = 8388608;
    u16* q_att = (u16*)d_ws;
    u16* k_att = q_att + M8;
    u16* v_t   = k_att + M8;
    u16* Xb    = v_t   + M8;            // Xb dead after qkv -> ctx aliases it
    u16* ctx   = Xb;
    u16* Wcat  = Xb + M8;
    u16* Wob   = Wcat + 3 * 1048576;

    convert<<<dim3(3072), 256, 0, stream>>>(X, Wq, Wk, Wv, Wo, Xb, Wcat, Wob);
    qkv_gemm10<<<dim3(24, 64), 256, 0, stream>>>(Xb, Wcat, bq, bk, bv,
                                                 q_att, k_att, v_t);
    attn5<<<dim3(64, 8), 256, 0, stream>>>(q_att, k_att, v_t, ctx);
    out_gemm10<<<dim3(8, 64), 256, 0, stream>>>(ctx, Wob, bo, (float*)d_out);
}

// Round 5
// 238.788 us; speedup vs baseline: 1.0134x; 1.0134x over previous
//
#include <hip/hip_runtime.h>

// GPT2 grouped-query attention, bf16 MFMA pipeline, round 12.
// R12: qkv back to 32KB/3-blocks-per-CU regime (R11's 64KB dbuf lost more
// occupancy than the pipeline gained), but now with within-block drain
// overlap at single-buffer cost: read all frags -> barrier -> DMA t+1 into
// same buffer -> sched_barrier -> 32 MFMA (covers the drain) -> barrier.
// out_gemm stays R11-dbuf (512 blocks = 1 exact round at 2/CU: improved ~9us).
// attn5/convert unchanged from R10.
// ws (u16 elems): q_att[8M] | k_att[8M] | v_t[8M] | Xb/ctx[8M] | Wcat[3M] | Wob[1M]

typedef __attribute__((ext_vector_type(8))) short short8;
typedef __attribute__((ext_vector_type(4))) float f32x4;
typedef unsigned int u32;
typedef unsigned short u16;

#define MFMA16(a, b, c) __builtin_amdgcn_mfma_f32_16x16x32_bf16((a), (b), (c), 0, 0, 0)

union S8 { short8 s; uint2 v[2]; u32 u[4]; };

__device__ __forceinline__ u32 f2bf1(float x) {
    union { float f; u32 u; } v; v.f = x;
    return (v.u + 0x7fffu + ((v.u >> 16) & 1u)) >> 16;   // RNE
}

__device__ __forceinline__ u32 cvtpk(float lo, float hi) {
    u32 r;
    asm("v_cvt_pk_bf16_f32 %0, %1, %2" : "=v"(r) : "v"(lo), "v"(hi));
    return r;
}

__device__ __forceinline__ void gld16(u16* lds, const u16* g) {
    __builtin_amdgcn_global_load_lds(
        (const __attribute__((address_space(1))) unsigned int*)(g),
        (__attribute__((address_space(3))) unsigned int*)(lds),
        16, 0, 0);
}

// ---------------------------------------------------------------------------
// Kernel 0: fp32 -> bf16 convert.
// ---------------------------------------------------------------------------
__global__ __launch_bounds__(256) void convert(
    const float* __restrict__ X, const float* __restrict__ Wq,
    const float* __restrict__ Wk, const float* __restrict__ Wv,
    const float* __restrict__ Wo,
    u16* __restrict__ Xb, u16* __restrict__ Wcat, u16* __restrict__ Wob)
{
    const size_t M8 = 8388608, M1 = 1048576;
    size_t i = ((size_t)blockIdx.x * 256 + threadIdx.x) * 16;
    const float* src; u16* dst;
    if (i < M8)              { src = X  + i;                dst = Xb   + i; }
    else if (i < M8 + M1)    { src = Wq + (i - M8);         dst = Wcat + (i - M8); }
    else if (i < M8 + 2*M1)  { src = Wk + (i - M8 - M1);    dst = Wcat + (i - M8); }
    else if (i < M8 + 3*M1)  { src = Wv + (i - M8 - 2*M1);  dst = Wcat + (i - M8); }
    else                     { src = Wo + (i - M8 - 3*M1);  dst = Wob  + (i - M8 - 3*M1); }
#pragma unroll
    for (int j = 0; j < 2; ++j) {
        float4 a = ((const float4*)src)[2 * j];
        float4 b = ((const float4*)src)[2 * j + 1];
        uint4 o;
        o.x = f2bf1(a.x) | (f2bf1(a.y) << 16);
        o.y = f2bf1(a.z) | (f2bf1(a.w) << 16);
        o.z = f2bf1(b.x) | (f2bf1(b.y) << 16);
        o.w = f2bf1(b.z) | (f2bf1(b.w) << 16);
        ((uint4*)dst)[j] = o;
    }
}

// ---------------------------------------------------------------------------
// Kernel 1: fused QKV GEMM. C[8192][3072] = Xb @ Wcat^T. 128x128 tile, BK=64,
// zero-conflict swizzle, SINGLE 32KB buffer with within-step overlap:
// frag-reads -> barrier -> DMA(t+1, same buf) -> sched_barrier -> MFMA
// (covers DMA drain) -> barrier(vmcnt0). 3 blocks/CU, 1536 = 2 exact rounds.
// q/k layout: [bh][g][dp'] with dp' = 2*dh + (s&1); v_t: [bh][dp][g-sigma].
// ---------------------------------------------------------------------------
__global__ __launch_bounds__(256, 3) void qkv_gemm11(
    const u16* __restrict__ Xb, const u16* __restrict__ Wcat,
    const float* __restrict__ b0, const float* __restrict__ b1,
    const float* __restrict__ b2,
    u16* __restrict__ q_att, u16* __restrict__ k_att, u16* __restrict__ v_t)
{
    const int nb = blockIdx.x, mb = blockIdx.y;
    const int mat = nb >> 3;

    __shared__ __align__(16) u16 As[128 * 64];   // 16 KB
    __shared__ __align__(16) u16 Bs[128 * 64];   // 16 KB

    const int t = threadIdx.x, wave = t >> 6, lane = t & 63;
    const int l15 = lane & 15, quad = lane >> 4;
    const int wm = (wave >> 1) * 64, wn = (wave & 1) * 64;

    const int srow = t >> 3;                               // 0..31
    const int scol = ((t & 7) ^ (srow & 7)) * 8;           // swizzled src chunk

    const u16* Ab = Xb   + (size_t)(mb * 128) * 1024;
    const u16* Bb = Wcat + (size_t)(nb * 128) * 1024;

    const int swz = l15 & 7;

#define QSTAGE(k0_) do {                                                      \
        _Pragma("unroll")                                                     \
        for (int c_ = 0; c_ < 4; ++c_) {                                      \
            size_t so_ = (size_t)(c_ * 32 + srow) * 1024 + (k0_) + scol;      \
            gld16(As + wave * 512 + c_ * 2048, Ab + so_);                     \
            gld16(Bs + wave * 512 + c_ * 2048, Bb + so_);                     \
        }                                                                     \
    } while (0)

    f32x4 acc[4][4] = {};

    QSTAGE(0);
    __syncthreads();                     // tile 0 staged & visible

    for (int kt = 0; kt < 16; ++kt) {
        // 1) pull all of tile kt into registers
        short8 af[4][2], bf[4][2];
#pragma unroll
        for (int ks = 0; ks < 2; ++ks) {
            const int ck = ((ks * 4 + quad) ^ swz) * 8;
#pragma unroll
            for (int mt = 0; mt < 4; ++mt)
                af[mt][ks] = *(const short8*)(As + (wm + mt * 16 + l15) * 64 + ck);
#pragma unroll
            for (int nt = 0; nt < 4; ++nt)
                bf[nt][ks] = *(const short8*)(Bs + (wn + nt * 16 + l15) * 64 + ck);
        }

        if (kt + 1 < 16) {
            // 2) all waves done reading LDS (implicit lgkmcnt(0) drain)
            __syncthreads();
            // 3) DMA tile kt+1 into the same buffer; flies under the MFMAs
            QSTAGE((kt + 1) * 64);
        }
        __builtin_amdgcn_sched_barrier(0);   // MFMA must not hoist above DMA issue

        // 4) compute on registers only — covers the DMA drain
#pragma unroll
        for (int ks = 0; ks < 2; ++ks)
#pragma unroll
            for (int mt = 0; mt < 4; ++mt)
#pragma unroll
                for (int nt = 0; nt < 4; ++nt)
                    acc[mt][nt] = MFMA16(af[mt][ks], bf[nt][ks], acc[mt][nt]);

        // 5) drain (implicit vmcnt(0)): tile kt+1 fully in LDS
        if (kt + 1 < 16) __syncthreads();
    }
#undef QSTAGE

    const float* bias = (mat == 0) ? b0 : (mat == 1) ? b1 : b2;
    const float scl = (mat == 0) ? 0.125f : 1.0f;
#pragma unroll
    for (int nt = 0; nt < 4; ++nt) {
        int colm = (nb & 7) * 128 + wn + nt * 16 + l15;   // feature = h*64+dh
        float bv = bias[colm];
        int h = colm >> 6, dh = colm & 63;
#pragma unroll
        for (int mt = 0; mt < 4; ++mt) {
            int row0 = mb * 128 + wm + mt * 16 + quad * 4;
            int b = row0 >> 11, s0 = row0 & 2047;
            int bh = b * 16 + h, g0 = s0 >> 1;                // even
            float v0 = (acc[mt][nt][0] + bv) * scl, v1 = (acc[mt][nt][1] + bv) * scl;
            float v2 = (acc[mt][nt][2] + bv) * scl, v3 = (acc[mt][nt][3] + bv) * scl;
            if (mat == 2) {
                u32 w0 = f2bf1(v0) | (f2bf1(v2) << 16);
                u32 w1 = f2bf1(v1) | (f2bf1(v3) << 16);
                int j6 = g0 & 63;
                int gp = (g0 & ~63) + (j6 & 32) + ((j6 >> 2) & 3) * 8
                       + ((j6 >> 4) & 1) * 4 + (j6 & 3);      // sigma-permuted
                *(u32*)(v_t + ((size_t)(bh * 128 + dh) * 1024 + gp)) = w0;
                *(u32*)(v_t + ((size_t)(bh * 128 + dh + 64) * 1024 + gp)) = w1;
            } else {
                u16* dst = (mat == 0) ? q_att : k_att;
                u32 w0 = f2bf1(v0) | (f2bf1(v1) << 16);
                u32 w1 = f2bf1(v2) | (f2bf1(v3) << 16);
                size_t base = ((size_t)bh * 1024 + g0) * 128 + 2 * dh;
                *(u32*)(dst + base) = w0;
                *(u32*)(dst + base + 128) = w1;
            }
        }
    }
}

// ---------------------------------------------------------------------------
// Kernel 2: flash attention, R10 structure (unchanged). QBLK=128/block,
// dbuf K/V LDS, shared ds_reads across 2 q-groups, cvt_pk packing,
// defer-max (THR=8), setprio on MFMA. grid (64 bh, 8 qb).
// ---------------------------------------------------------------------------
__global__ __launch_bounds__(256, 2) void attn5(
    const u16* __restrict__ q_att, const u16* __restrict__ k_att,
    const u16* __restrict__ v_t, u16* __restrict__ ctx)
{
    const int bh = blockIdx.x, qb = blockIdx.y;
    const u16* Q = q_att + (size_t)bh * 131072;
    const u16* K = k_att + (size_t)bh * 131072;
    const u16* V = v_t  + (size_t)bh * 131072;     // [d'=128][g-sigma-permuted]

    __shared__ __align__(16) u16 Ks[2][64 * 128];  // 32 KB
    __shared__ __align__(16) u16 Vs[2][128 * 64];  // 32 KB

    const int t = threadIdx.x, wave = t >> 6, lane = t & 63;
    const int l15 = lane & 15, quad = lane >> 4;

    int offK[4], offV[4];
#pragma unroll
    for (int j = 0; j < 4; ++j) {
        int ck = wave * 4 + j;
        int rowK = ck * 4 + (lane >> 4);                       // 0..63
        offK[j] = rowK * 128 + (((lane & 15) ^ (rowK & 15)) * 8);
        int rowV = ck * 8 + (lane >> 3);                       // d' 0..127
        offV[j] = rowV * 1024 + (((lane & 7) ^ ((lane >> 3) & 7)) * 8);
    }

#define ASTAGE(pp, kt) do {                                                   \
        const u16* Kt_ = K + (size_t)(kt) * 8192;                             \
        const u16* Vt_ = V + (size_t)(kt) * 64;                               \
        _Pragma("unroll")                                                     \
        for (int j_ = 0; j_ < 4; ++j_) {                                      \
            gld16(&Ks[(pp)][(wave * 4 + j_) * 512], Kt_ + offK[j_]);          \
            gld16(&Vs[(pp)][(wave * 4 + j_) * 512], Vt_ + offV[j_]);          \
        }                                                                     \
    } while (0)

    short8 bq[2][4];
#pragma unroll
    for (int qg = 0; qg < 2; ++qg) {
        const int qr = qb * 128 + wave * 32 + qg * 16 + l15;
#pragma unroll
        for (int kb = 0; kb < 4; ++kb)
            bq[qg][kb] = *(const short8*)(Q + (size_t)qr * 128 + kb * 32 + quad * 8);
    }

    f32x4 accO[2][8] = {};
    float m_i[2] = {-1e30f, -1e30f}, l_i[2] = {0.0f, 0.0f};

    ASTAGE(0, 0);
    __syncthreads();

    for (int kt = 0; kt < 16; ++kt) {
        const int p = kt & 1;
        if (kt + 1 < 16) ASTAGE(p ^ 1, kt + 1);
        const u16* Ksp = &Ks[p][0];
        const u16* Vsp = &Vs[p][0];

        f32x4 accS[2][4] = {};
        __builtin_amdgcn_s_setprio(1);
#pragma unroll
        for (int kf = 0; kf < 4; ++kf)
#pragma unroll
            for (int kb = 0; kb < 4; ++kb) {
                short8 ak = *(const short8*)(Ksp + (kf * 16 + l15) * 128
                                             + (((kb * 4 + quad) ^ l15) * 8));
                accS[0][kf] = MFMA16(ak, bq[0][kb], accS[0][kf]);
                accS[1][kf] = MFMA16(ak, bq[1][kb], accS[1][kf]);
            }
        __builtin_amdgcn_s_setprio(0);

        u32 pb[2][8];
#pragma unroll
        for (int qg = 0; qg < 2; ++qg) {
            float mloc = -1e30f;
#pragma unroll
            for (int kf = 0; kf < 4; ++kf)
                mloc = fmaxf(mloc, fmaxf(fmaxf(accS[qg][kf][0], accS[qg][kf][1]),
                                         fmaxf(accS[qg][kf][2], accS[qg][kf][3])));
            mloc = fmaxf(mloc, __shfl_xor(mloc, 16));
            mloc = fmaxf(mloc, __shfl_xor(mloc, 32));

            if (!__all(mloc - m_i[qg] <= 8.0f)) {
                float mn = fmaxf(m_i[qg], mloc);
                float alpha = __expf(m_i[qg] - mn);
#pragma unroll
                for (int f = 0; f < 8; ++f) {
                    accO[qg][f][0] *= alpha; accO[qg][f][1] *= alpha;
                    accO[qg][f][2] *= alpha; accO[qg][f][3] *= alpha;
                }
                l_i[qg] *= alpha;
                m_i[qg] = mn;
            }

            float lsum = 0.0f;
            const float mi = m_i[qg];
#pragma unroll
            for (int kf = 0; kf < 4; ++kf) {
                float p0 = __expf(accS[qg][kf][0] - mi);
                float p1 = __expf(accS[qg][kf][1] - mi);
                float p2 = __expf(accS[qg][kf][2] - mi);
                float p3 = __expf(accS[qg][kf][3] - mi);
                lsum += (p0 + p1) + (p2 + p3);
                pb[qg][kf * 2]     = cvtpk(p0, p1);
                pb[qg][kf * 2 + 1] = cvtpk(p2, p3);
            }
            lsum += __shfl_xor(lsum, 16);
            lsum += __shfl_xor(lsum, 32);
            l_i[qg] += lsum;
        }

        S8 bp00, bp01, bp10, bp11;
        bp00.u[0] = pb[0][0]; bp00.u[1] = pb[0][1]; bp00.u[2] = pb[0][2]; bp00.u[3] = pb[0][3];
        bp01.u[0] = pb[0][4]; bp01.u[1] = pb[0][5]; bp01.u[2] = pb[0][6]; bp01.u[3] = pb[0][7];
        bp10.u[0] = pb[1][0]; bp10.u[1] = pb[1][1]; bp10.u[2] = pb[1][2]; bp10.u[3] = pb[1][3];
        bp11.u[0] = pb[1][4]; bp11.u[1] = pb[1][5]; bp11.u[2] = pb[1][6]; bp11.u[3] = pb[1][7];
        const int l7 = l15 & 7;
        __builtin_amdgcn_s_setprio(1);
#pragma unroll
        for (int df = 0; df < 8; ++df) {
            const u16* vrow = Vsp + (df * 16 + l15) * 64;
            short8 av0 = *(const short8*)(vrow + ((quad ^ l7) * 8));
            short8 av1 = *(const short8*)(vrow + (((quad + 4) ^ l7) * 8));
            accO[0][df] = MFMA16(av0, bp00.s, accO[0][df]);
            accO[0][df] = MFMA16(av1, bp01.s, accO[0][df]);
            accO[1][df] = MFMA16(av0, bp10.s, accO[1][df]);
            accO[1][df] = MFMA16(av1, bp11.s, accO[1][df]);
        }
        __builtin_amdgcn_s_setprio(0);

        if (kt + 1 < 16) __syncthreads();
    }
#undef ASTAGE

    const int h = bh & 15, b = bh >> 4;
#pragma unroll
    for (int qg = 0; qg < 2; ++qg) {
        const int qr = qb * 128 + wave * 32 + qg * 16 + l15;
        float inv = 1.0f / l_i[qg];
        size_t base = ((size_t)(b * 2048 + 2 * qr + (h >> 3))) * 1024 + (h & 7) * 128;
#pragma unroll
        for (int df = 0; df < 8; ++df) {
            int dp = df * 16 + quad * 4;
            uint2 w;
            w.x = f2bf1(accO[qg][df][0] * inv) | (f2bf1(accO[qg][df][1] * inv) << 16);
            w.y = f2bf1(accO[qg][df][2] * inv) | (f2bf1(accO[qg][df][3] * inv) << 16);
            *(uint2*)(ctx + base + dp) = w;
        }
    }
}

// ---------------------------------------------------------------------------
// Kernel 3: out = ctx(bf16) @ Wob^T + bo -> fp32. dbuf single-barrier (R11).
// grid (8,64) = 512 blocks = exactly 1 round at 2/CU.
// ---------------------------------------------------------------------------
__global__ __launch_bounds__(256, 2) void out_gemm10(
    const u16* __restrict__ ctx, const u16* __restrict__ Wob,
    const float* __restrict__ bo, float* __restrict__ out)
{
    const int nb = blockIdx.x, mb = blockIdx.y;
    __shared__ __align__(16) u16 As[2][128 * 64];
    __shared__ __align__(16) u16 Bs[2][128 * 64];
    const int t = threadIdx.x, wave = t >> 6, lane = t & 63;
    const int l15 = lane & 15, quad = lane >> 4;
    const int wm = (wave >> 1) * 64, wn = (wave & 1) * 64;

    const int srow = t >> 3;
    const int scol = ((t & 7) ^ (srow & 7)) * 8;

    const u16* Ab = ctx + (size_t)(mb * 128) * 1024;
    const u16* Bb = Wob + (size_t)(nb * 128) * 1024;

    const int swz = l15 & 7;

#define OSTAGE(pp, k0_) do {                                                  \
        _Pragma("unroll")                                                     \
        for (int c_ = 0; c_ < 4; ++c_) {                                      \
            size_t so_ = (size_t)(c_ * 32 + srow) * 1024 + (k0_) + scol;      \
            gld16(&As[(pp)][wave * 512 + c_ * 2048], Ab + so_);               \
            gld16(&Bs[(pp)][wave * 512 + c_ * 2048], Bb + so_);               \
        }                                                                     \
    } while (0)

    f32x4 acc[4][4] = {};

    OSTAGE(0, 0);
    __syncthreads();

    for (int kt = 0; kt < 16; ++kt) {
        const int p = kt & 1;
        if (kt + 1 < 16) OSTAGE(p ^ 1, (kt + 1) * 64);
        const u16* Asp = &As[p][0];
        const u16* Bsp = &Bs[p][0];

#pragma unroll
        for (int ks = 0; ks < 2; ++ks) {
            short8 af[4], bf[4];
            const int ck = ((ks * 4 + quad) ^ swz) * 8;
#pragma unroll
            for (int mt = 0; mt < 4; ++mt)
                af[mt] = *(const short8*)(Asp + (wm + mt * 16 + l15) * 64 + ck);
#pragma unroll
            for (int nt = 0; nt < 4; ++nt)
                bf[nt] = *(const short8*)(Bsp + (wn + nt * 16 + l15) * 64 + ck);
#pragma unroll
            for (int mt = 0; mt < 4; ++mt)
#pragma unroll
                for (int nt = 0; nt < 4; ++nt)
                    acc[mt][nt] = MFMA16(af[mt], bf[nt], acc[mt][nt]);
        }

        if (kt + 1 < 16) __syncthreads();
    }
#undef OSTAGE

#pragma unroll
    for (int nt = 0; nt < 4; ++nt) {
        int col = nb * 128 + wn + nt * 16 + l15;
        float bv = bo[col];
#pragma unroll
        for (int mt = 0; mt < 4; ++mt)
#pragma unroll
            for (int r = 0; r < 4; ++r) {
                int row = mb * 128 + wm + mt * 16 + quad * 4 + r;
                out[(size_t)row * 1024 + col] = acc[mt][nt][r] + bv;
            }
    }
}

// ---------------------------------------------------------------------------
extern "C" void kernel_launch(void* const* d_in, const int* in_sizes, int n_in,
                              void* d_out, int out_size, void* d_ws, size_t ws_size,
                              hipStream_t stream)
{
    const float* X  = (const float*)d_in[0];
    const float* Wq = (const float*)d_in[1];
    const float* bq = (const float*)d_in[2];
    const float* Wk = (const float*)d_in[3];
    const float* bk = (const float*)d_in[4];
    const float* Wv = (const float*)d_in[5];
    const float* bv = (const float*)d_in[6];
    const float* Wo = (const float*)d_in[7];
    const float* bo = (const float*)d_in[8];

    const size_t M8 = 8388608;
    u16* q_att = (u16*)d_ws;
    u16* k_att = q_att + M8;
    u16* v_t   = k_att + M8;
    u16* Xb    = v_t   + M8;            // Xb dead after qkv -> ctx aliases it
    u16* ctx   = Xb;
    u16* Wcat  = Xb + M8;
    u16* Wob   = Wcat + 3 * 1048576;

    convert<<<dim3(3072), 256, 0, stream>>>(X, Wq, Wk, Wv, Wo, Xb, Wcat, Wob);
    qkv_gemm11<<<dim3(24, 64), 256, 0, stream>>>(Xb, Wcat, bq, bk, bv,
                                                 q_att, k_att, v_t);
    attn5<<<dim3(64, 8), 256, 0, stream>>>(q_att, k_att, v_t, ctx);
    out_gemm10<<<dim3(8, 64), 256, 0, stream>>>(ctx, Wob, bo, (float*)d_out);
}